// Round 4
// baseline (3184.874 us; speedup 1.0000x reference)
//
#include <hip/hip_runtime.h>

// LSTM predictor: B=2048 rows, T=2048 + 128 future, H=51.
// TWO WAVES per batch row (block=128, grid=2048). Wave 0 owns gates i,f;
// wave 1 owns gates g,o. Lane k owns unit k: 102 weights/lane stored as 52
// float2 pairs -> v_pk_fma_f32 (2 FMAs/inst). Hot set ~130 regs fits the
// 128-VGPR tier (round-3 failure: 204 weights/lane forced ~110 into AGPRs,
// +1 move per weight per step). Per step: 13 uniform ds_read_b128 h
// broadcasts, 52 pk-FMAs, own-gate activations, one double-buffered LDS
// gate exchange + ONE __syncthreads, redundant c/h update in both waves
// (keeps h wave-local). fc output batched via transpose-stash (wave 0).

typedef float v2f __attribute__((ext_vector_type(2)));
typedef float v4f __attribute__((ext_vector_type(4)));

constexpr int Hh = 51;

__device__ __forceinline__ float fexp2(float x){ return __builtin_amdgcn_exp2f(x); }
__device__ __forceinline__ float frcp(float x) { return __builtin_amdgcn_rcpf(x); }
// sigmoid(x) = 1/(1+2^(-x*log2e))
__device__ __forceinline__ float sigm(float x) { return frcp(1.f + fexp2(-1.44269504f * x)); }
// tanh(x) = 1 - 2/(1+2^(2x*log2e))
__device__ __forceinline__ float tanh_f(float x){ return 1.f - 2.f * frcp(1.f + fexp2(2.88539008f * x)); }

__device__ __forceinline__ float rdlane(float v, int lane){
  return __int_as_float(__builtin_amdgcn_readlane(__float_as_int(v), lane));
}

__global__ __launch_bounds__(128)
void lstm_kernel(const float* __restrict__ x,
                 const float* __restrict__ W_ih,
                 const float* __restrict__ W_hh,
                 const float* __restrict__ b_ih,
                 const float* __restrict__ b_hh,
                 const float* __restrict__ fc_w,
                 const float* __restrict__ fc_b,
                 float* __restrict__ out,
                 int T, int OT)
{
  const int wv  = threadIdx.x >> 6;   // 0: gates i,f   1: gates g,o
  const int k   = threadIdx.x & 63;   // lane = hidden unit
  const int row = blockIdx.x;         // batch row

  __shared__ __align__(16) float hbuf[2][64];   // per-wave h copy
  __shared__ __align__(16) v2f   gx[2][2][64];  // [buf][wave][lane] = (act0,act1)
  __shared__ float st[64][65];                  // fc stash (wave 0 only)
  __shared__ float xshare;                      // main->future handoff

  hbuf[wv][k] = 0.f;   // own copy, incl. slot 51 (read by pair 25, weight=0)

  // ---- weights: 2 gate rows per lane as float2 pairs (pad j=51 with 0)
  const int kc = (k < Hh) ? k : (Hh - 1);       // clamp, no divergence
  const int rA = (wv * 2 + 0) * Hh + kc;
  const int rB = (wv * 2 + 1) * Hh + kc;
  v2f wA[26], wB[26];
#pragma unroll
  for (int m = 0; m < 25; ++m) {
    wA[m] = (v2f){W_hh[rA * Hh + 2*m], W_hh[rA * Hh + 2*m + 1]};
    wB[m] = (v2f){W_hh[rB * Hh + 2*m], W_hh[rB * Hh + 2*m + 1]};
  }
  wA[25] = (v2f){W_hh[rA * Hh + 50], 0.f};
  wB[25] = (v2f){W_hh[rB * Hh + 50], 0.f};
  const float wiA = W_ih[rA], wiB = W_ih[rB];
  const float bsA = b_ih[rA] + b_hh[rA];
  const float bsB = b_ih[rB] + b_hh[rB];
  const float fcw = (k < Hh) ? fc_w[k] : 0.f;
  const float fcb = fc_b[0];

  float c = 0.f, h = 0.f;

  auto cell = [&](float xt, int buf) {
    v2f accA = (v2f){fmaf(xt, wiA, bsA), 0.f};
    v2f accB = (v2f){fmaf(xt, wiB, bsB), 0.f};
    const v4f* hb4 = (const v4f*)(&hbuf[wv][0]);
#pragma unroll
    for (int q = 0; q < 13; ++q) {
      const v4f hv = hb4[q];           // uniform-address broadcast read
      const v2f hlo = (v2f){hv.x, hv.y};
      const v2f hhi = (v2f){hv.z, hv.w};
      accA = __builtin_elementwise_fma(wA[2*q],     hlo, accA);
      accA = __builtin_elementwise_fma(wA[2*q + 1], hhi, accA);
      accB = __builtin_elementwise_fma(wB[2*q],     hlo, accB);
      accB = __builtin_elementwise_fma(wB[2*q + 1], hhi, accB);
    }
    const float A  = accA.x + accA.y;
    const float Bv = accB.x + accB.y;

    // own-gate activations (wave-uniform branch)
    float act0, act1;
    if (wv == 0) { act0 = sigm(A);   act1 = sigm(Bv); }   // i, f
    else         { act0 = tanh_f(A); act1 = sigm(Bv); }   // g, o

    gx[buf][wv][k] = (v2f){act0, act1};
    __syncthreads();                   // one barrier per step
    const v2f other = gx[buf][1 - wv][k];

    float ia, fa, ga, oa;
    if (wv == 0) { ia = act0;    fa = act1;    ga = other.x; oa = other.y; }
    else         { ia = other.x; fa = other.y; ga = act0;    oa = act1;    }

    c = fmaf(fa, c, ia * ga);
    h = oa * tanh_f(c);

    asm volatile("" ::: "memory");
    hbuf[wv][k] = h;                   // publish for next step (same-wave FIFO)
    asm volatile("" ::: "memory");
  };

  // ---- main phase: T steps in chunks of 64
  float s = fcb;
  for (int tc = 0; tc < T; tc += 64) {
    const float xv = x[(long)row * T + tc + k];   // coalesced chunk load
#pragma unroll 1
    for (int i = 0; i < 64; ++i) {
      cell(rdlane(xv, i), (tc + i) & 1);
      if (wv == 0) st[k][i] = h * fcw;            // conflict-free (stride 65)
    }
    if (wv == 0) {                                // transpose-reduce + store
      s = fcb;
#pragma unroll
      for (int j = 0; j < 64; ++j) s += st[j][k];
      out[(long)row * OT + tc + k] = s;           // coalesced
    }
  }

  // ---- handoff out[T-1] to both waves
  if (threadIdx.x == 0) xshare = rdlane(s, 63);
  __syncthreads();
  float out_prev = xshare;

  // ---- future phase: feedback out -> x (128 steps = 2 chunks of 64)
  float obuf = 0.f;
  for (int t = T; t < OT; ++t) {
    cell(out_prev, t & 1);
    float p = h * fcw;
#pragma unroll
    for (int off = 32; off > 0; off >>= 1) p += __shfl_xor(p, off, 64);
    const float out_t = p + fcb;
    obuf = (k == (t & 63)) ? out_t : obuf;
    if (((t & 63) == 63) && wv == 0)
      out[(long)row * OT + (t - 63) + k] = obuf;  // coalesced
    out_prev = out_t;
  }
}

extern "C" void kernel_launch(void* const* d_in, const int* in_sizes, int n_in,
                              void* d_out, int out_size, void* d_ws, size_t ws_size,
                              hipStream_t stream) {
  const float* x    = (const float*)d_in[0];
  const float* W_ih = (const float*)d_in[1];
  const float* W_hh = (const float*)d_in[2];
  const float* b_ih = (const float*)d_in[3];
  const float* b_hh = (const float*)d_in[4];
  const float* fc_w = (const float*)d_in[5];
  const float* fc_b = (const float*)d_in[6];
  float* out = (float*)d_out;

  const int B  = 2048;
  const int T  = in_sizes[0] / B;   // 2048
  const int OT = out_size / B;      // 2176

  lstm_kernel<<<dim3(B), dim3(128), 0, stream>>>(x, W_ih, W_hh, b_ih, b_hh,
                                                 fc_w, fc_b, out, T, OT);
}

// Round 5
// 1477.979 us; speedup vs baseline: 2.1549x; 2.1549x over previous
//
#include <hip/hip_runtime.h>

// LSTM predictor: B=2048 rows, T=2048 + 128 future, H=51.
// ONE WAVE per batch row (grid 2048 x 64). Barrier-free (round-4 lesson:
// per-step __syncthreads serializes the recurrence; 41% VALUBusy).
// Lane k owns unit k; all four W_hh gate rows live in VGPRs as 102 float2
// pairs -> v_pk_fma_f32 (round-4 win, kept). __launch_bounds__(64, 1) drops
// the allocator's occupancy floor to 1 wave/EU = 512-reg budget so the
// ~240-reg hot set stays in arch VGPRs (rounds 2/3 failure: 128-VGPR cap
// pushed ~110 weights into AGPRs, +1 v_accvgpr_read per use per step).
// ~240 regs still gives the 2 waves/SIMD the grid needs.
// h broadcast via per-block LDS vector (uniform-address float4 reads).
// fc output batched: per-step conflict-free stash, per-64-step transposed
// column-sum + coalesced store.

typedef float v2f __attribute__((ext_vector_type(2)));
typedef float v4f __attribute__((ext_vector_type(4)));

constexpr int Hh = 51;

__device__ __forceinline__ float fexp2(float x){ return __builtin_amdgcn_exp2f(x); }
__device__ __forceinline__ float frcp(float x) { return __builtin_amdgcn_rcpf(x); }
// sigmoid(x) = 1/(1+2^(-x*log2e))
__device__ __forceinline__ float sigm(float x) { return frcp(1.f + fexp2(-1.44269504f * x)); }
// tanh(x) = 1 - 2/(1+2^(2x*log2e))
__device__ __forceinline__ float tanh_f(float x){ return 1.f - 2.f * frcp(1.f + fexp2(2.88539008f * x)); }

__device__ __forceinline__ float rdlane(float v, int lane){
  return __int_as_float(__builtin_amdgcn_readlane(__float_as_int(v), lane));
}

__global__ __launch_bounds__(64, 1)
void lstm_kernel(const float* __restrict__ x,
                 const float* __restrict__ W_ih,
                 const float* __restrict__ W_hh,
                 const float* __restrict__ b_ih,
                 const float* __restrict__ b_hh,
                 const float* __restrict__ fc_w,
                 const float* __restrict__ fc_b,
                 float* __restrict__ out,
                 int T, int OT)
{
  const int k   = threadIdx.x;   // lane = hidden unit
  const int row = blockIdx.x;    // batch row

  __shared__ __align__(16) float hbuf[64];    // h vector; [52..63] junk, never read
  __shared__ float st[64][65];                // fc stash: st[lane][step_in_chunk]

  hbuf[k] = 0.f;

  // ---- weights: 4 gate rows per lane as float2 pairs (pair 25: {w[50], 0})
  const int kc = (k < Hh) ? k : (Hh - 1);     // clamp, no divergence
  v2f w0[26], w1[26], w2[26], w3[26];
  const long r0 = (long)(0 * Hh + kc) * Hh;
  const long r1 = (long)(1 * Hh + kc) * Hh;
  const long r2 = (long)(2 * Hh + kc) * Hh;
  const long r3 = (long)(3 * Hh + kc) * Hh;
#pragma unroll
  for (int m = 0; m < 25; ++m) {
    w0[m] = (v2f){W_hh[r0 + 2*m], W_hh[r0 + 2*m + 1]};
    w1[m] = (v2f){W_hh[r1 + 2*m], W_hh[r1 + 2*m + 1]};
    w2[m] = (v2f){W_hh[r2 + 2*m], W_hh[r2 + 2*m + 1]};
    w3[m] = (v2f){W_hh[r3 + 2*m], W_hh[r3 + 2*m + 1]};
  }
  w0[25] = (v2f){W_hh[r0 + 50], 0.f};
  w1[25] = (v2f){W_hh[r1 + 50], 0.f};
  w2[25] = (v2f){W_hh[r2 + 50], 0.f};
  w3[25] = (v2f){W_hh[r3 + 50], 0.f};
  const float wi0 = W_ih[0 * Hh + kc], wi1 = W_ih[1 * Hh + kc];
  const float wi2 = W_ih[2 * Hh + kc], wi3 = W_ih[3 * Hh + kc];
  const float bs0 = b_ih[0 * Hh + kc] + b_hh[0 * Hh + kc];
  const float bs1 = b_ih[1 * Hh + kc] + b_hh[1 * Hh + kc];
  const float bs2 = b_ih[2 * Hh + kc] + b_hh[2 * Hh + kc];
  const float bs3 = b_ih[3 * Hh + kc] + b_hh[3 * Hh + kc];
  const float fcw = (k < Hh) ? fc_w[k] : 0.f;
  const float fcb = fc_b[0];

  float c = 0.f, h = 0.f;

  auto cell = [&](float xt) {
    v2f a0 = (v2f){fmaf(xt, wi0, bs0), 0.f};
    v2f a1 = (v2f){fmaf(xt, wi1, bs1), 0.f};
    v2f a2 = (v2f){fmaf(xt, wi2, bs2), 0.f};
    v2f a3 = (v2f){fmaf(xt, wi3, bs3), 0.f};
    const v4f* hb4 = (const v4f*)hbuf;
#pragma unroll
    for (int q = 0; q < 13; ++q) {
      const v4f hv = hb4[q];           // uniform-address broadcast read
      const v2f hlo = (v2f){hv.x, hv.y};
      const v2f hhi = (v2f){hv.z, hv.w};
      a0 = __builtin_elementwise_fma(w0[2*q], hlo, a0);
      a1 = __builtin_elementwise_fma(w1[2*q], hlo, a1);
      a2 = __builtin_elementwise_fma(w2[2*q], hlo, a2);
      a3 = __builtin_elementwise_fma(w3[2*q], hlo, a3);
      if (q < 12) {                    // pair 25 hi-half: weight 0, skip nothing
        a0 = __builtin_elementwise_fma(w0[2*q + 1], hhi, a0);
        a1 = __builtin_elementwise_fma(w1[2*q + 1], hhi, a1);
        a2 = __builtin_elementwise_fma(w2[2*q + 1], hhi, a2);
        a3 = __builtin_elementwise_fma(w3[2*q + 1], hhi, a3);
      } else {
        a0 = __builtin_elementwise_fma(w0[25], hhi, a0);
        a1 = __builtin_elementwise_fma(w1[25], hhi, a1);
        a2 = __builtin_elementwise_fma(w2[25], hhi, a2);
        a3 = __builtin_elementwise_fma(w3[25], hhi, a3);
      }
    }
    const float ia = sigm(a0.x + a0.y);
    const float fa = sigm(a1.x + a1.y);
    const float ga = tanh_f(a2.x + a2.y);
    const float oa = sigm(a3.x + a3.y);
    c = fmaf(fa, c, ia * ga);
    h = oa * tanh_f(c);
    asm volatile("" ::: "memory");
    hbuf[k] = h;                       // publish for next step (same-wave FIFO)
    asm volatile("" ::: "memory");
  };

  // ---- main phase: T steps in chunks of 64
  float s = fcb;
  for (int tc = 0; tc < T; tc += 64) {
    const float xv = x[(long)row * T + tc + k];   // coalesced chunk load
#pragma unroll 1
    for (int i = 0; i < 64; ++i) {
      cell(rdlane(xv, i));
      st[k][i] = h * fcw;              // conflict-free (stride 65)
    }
    // transpose-reduce: lane t sums column t -> out[tc + t]
    s = fcb;
#pragma unroll
    for (int j = 0; j < 64; ++j) s += st[j][k];   // conflict-free per j
    asm volatile("" ::: "memory");
    out[(long)row * OT + tc + k] = s;  // coalesced store
  }

  // ---- future phase: feedback out -> x, butterfly reduce each step
  float out_prev = rdlane(s, 63);      // out[T-1]
  float obuf = 0.f;
  for (int t = T; t < OT; ++t) {
    cell(out_prev);
    float p = h * fcw;
#pragma unroll
    for (int off = 32; off > 0; off >>= 1) p += __shfl_xor(p, off, 64);
    const float out_t = p + fcb;
    obuf = (k == (t & 63)) ? out_t : obuf;
    if ((t & 63) == 63)
      out[(long)row * OT + (t - 63) + k] = obuf;  // coalesced
    out_prev = out_t;
  }
}

extern "C" void kernel_launch(void* const* d_in, const int* in_sizes, int n_in,
                              void* d_out, int out_size, void* d_ws, size_t ws_size,
                              hipStream_t stream) {
  const float* x    = (const float*)d_in[0];
  const float* W_ih = (const float*)d_in[1];
  const float* W_hh = (const float*)d_in[2];
  const float* b_ih = (const float*)d_in[3];
  const float* b_hh = (const float*)d_in[4];
  const float* fc_w = (const float*)d_in[5];
  const float* fc_b = (const float*)d_in[6];
  float* out = (float*)d_out;

  const int B  = 2048;
  const int T  = in_sizes[0] / B;   // 2048
  const int OT = out_size / B;      // 2176

  lstm_kernel<<<dim3(B), dim3(64), 0, stream>>>(x, W_ih, W_hh, b_ih, b_hh,
                                                fc_w, fc_b, out, T, OT);
}

// Round 6
// 1299.292 us; speedup vs baseline: 2.4512x; 1.1375x over previous
//
#include <hip/hip_runtime.h>

// LSTM predictor: B=2048 rows, T=2048 + 128 future, H=51.
// ONE WAVE per batch row (grid 2048 x 64), barrier-free.
// Round-5 lesson: arch-VGPR allocation pins at 128 regardless of launch
// bounds; 204 fp32 weights/lane forced ~110 into AGPRs (+1 v_accvgpr_read
// per use per step = the measured 2.1x issue overhead). Fix: shrink the hot
// set under the cap — W_hh stored as packed f16 pairs (104 VGPRs) consumed
// by v_dot2_f32_f16 (2 MACs/inst, fp32 accumulate). h published to LDS as
// f16 (1 cvt + b16 write) and read via 7 uniform-address ds_read_b128
// broadcasts; each 32-bit word is a ready-made (h_2m, h_2m+1) dot2 operand.
// Biases, x path, c, and fc head stay fp32.

typedef _Float16 v2h __attribute__((ext_vector_type(2)));
typedef float    v4f __attribute__((ext_vector_type(4)));

constexpr int Hh = 51;

__device__ __forceinline__ float fexp2(float x){ return __builtin_amdgcn_exp2f(x); }
__device__ __forceinline__ float frcp(float x) { return __builtin_amdgcn_rcpf(x); }
// sigmoid(x) = 1/(1+2^(-x*log2e))
__device__ __forceinline__ float sigm(float x) { return frcp(1.f + fexp2(-1.44269504f * x)); }
// tanh(x) = 1 - 2/(1+2^(2x*log2e))
__device__ __forceinline__ float tanh_f(float x){ return 1.f - 2.f * frcp(1.f + fexp2(2.88539008f * x)); }

__device__ __forceinline__ float rdlane(float v, int lane){
  return __int_as_float(__builtin_amdgcn_readlane(__float_as_int(v), lane));
}

__device__ __forceinline__ v2h bch(float f){
  union { float f; v2h h; } u; u.f = f; return u.h;
}

#if __has_builtin(__builtin_amdgcn_fdot2)
__device__ __forceinline__ float dot2(v2h a, v2h b, float c){
  return __builtin_amdgcn_fdot2(a, b, c, false);
}
#else
__device__ __forceinline__ float dot2(v2h a, v2h b, float c){
  float r;
  asm("v_dot2_f32_f16 %0, %1, %2, %3" : "=v"(r) : "v"(a), "v"(b), "v"(c));
  return r;
}
#endif

__global__ __launch_bounds__(64)
__attribute__((amdgpu_waves_per_eu(1)))
void lstm_kernel(const float* __restrict__ x,
                 const float* __restrict__ W_ih,
                 const float* __restrict__ W_hh,
                 const float* __restrict__ b_ih,
                 const float* __restrict__ b_hh,
                 const float* __restrict__ fc_w,
                 const float* __restrict__ fc_b,
                 float* __restrict__ out,
                 int T, int OT)
{
  const int k   = threadIdx.x;   // lane = hidden unit
  const int row = blockIdx.x;    // batch row

  __shared__ __align__(16) _Float16 hbuf16[64];  // h as f16; [52..63] junk, never read
  __shared__ float st[64][65];                   // fc stash: st[lane][step_in_chunk]

  hbuf16[k] = (_Float16)0.f;

  // ---- weights: 4 gate rows per lane as f16 pairs (pair 25: {w[50], 0})
  const int kc = (k < Hh) ? k : (Hh - 1);        // clamp, no divergence
  v2h w0[26], w1[26], w2[26], w3[26];
  const long r0 = (long)(0 * Hh + kc) * Hh;
  const long r1 = (long)(1 * Hh + kc) * Hh;
  const long r2 = (long)(2 * Hh + kc) * Hh;
  const long r3 = (long)(3 * Hh + kc) * Hh;
#pragma unroll
  for (int m = 0; m < 25; ++m) {
    w0[m] = (v2h){(_Float16)W_hh[r0 + 2*m], (_Float16)W_hh[r0 + 2*m + 1]};
    w1[m] = (v2h){(_Float16)W_hh[r1 + 2*m], (_Float16)W_hh[r1 + 2*m + 1]};
    w2[m] = (v2h){(_Float16)W_hh[r2 + 2*m], (_Float16)W_hh[r2 + 2*m + 1]};
    w3[m] = (v2h){(_Float16)W_hh[r3 + 2*m], (_Float16)W_hh[r3 + 2*m + 1]};
  }
  w0[25] = (v2h){(_Float16)W_hh[r0 + 50], (_Float16)0.f};
  w1[25] = (v2h){(_Float16)W_hh[r1 + 50], (_Float16)0.f};
  w2[25] = (v2h){(_Float16)W_hh[r2 + 50], (_Float16)0.f};
  w3[25] = (v2h){(_Float16)W_hh[r3 + 50], (_Float16)0.f};
  const float wi0 = W_ih[0 * Hh + kc], wi1 = W_ih[1 * Hh + kc];
  const float wi2 = W_ih[2 * Hh + kc], wi3 = W_ih[3 * Hh + kc];
  const float bs0 = b_ih[0 * Hh + kc] + b_hh[0 * Hh + kc];
  const float bs1 = b_ih[1 * Hh + kc] + b_hh[1 * Hh + kc];
  const float bs2 = b_ih[2 * Hh + kc] + b_hh[2 * Hh + kc];
  const float bs3 = b_ih[3 * Hh + kc] + b_hh[3 * Hh + kc];
  const float fcw = (k < Hh) ? fc_w[k] : 0.f;
  const float fcb = fc_b[0];

  float c = 0.f, h = 0.f;

  auto cell = [&](float xt) {
    float a0 = fmaf(xt, wi0, bs0);
    float a1 = fmaf(xt, wi1, bs1);
    float a2 = fmaf(xt, wi2, bs2);
    float a3 = fmaf(xt, wi3, bs3);
    const v4f* hb4 = (const v4f*)hbuf16;   // 8 halfs per read, word = dot2 pair
#pragma unroll
    for (int q = 0; q < 7; ++q) {
      const v4f hv = hb4[q];               // uniform-address broadcast read
      const int p = 4 * q;                 // first h-pair index in this word
      const v2h h0 = bch(hv.x), h1 = bch(hv.y), h2 = bch(hv.z), h3 = bch(hv.w);
      a0 = dot2(w0[p], h0, a0);
      a1 = dot2(w1[p], h0, a1);
      a2 = dot2(w2[p], h0, a2);
      a3 = dot2(w3[p], h0, a3);
      if (p + 1 < 26) {
        a0 = dot2(w0[p+1], h1, a0); a1 = dot2(w1[p+1], h1, a1);
        a2 = dot2(w2[p+1], h1, a2); a3 = dot2(w3[p+1], h1, a3);
      }
      if (p + 2 < 26) {
        a0 = dot2(w0[p+2], h2, a0); a1 = dot2(w1[p+2], h2, a1);
        a2 = dot2(w2[p+2], h2, a2); a3 = dot2(w3[p+2], h2, a3);
      }
      if (p + 3 < 26) {
        a0 = dot2(w0[p+3], h3, a0); a1 = dot2(w1[p+3], h3, a1);
        a2 = dot2(w2[p+3], h3, a2); a3 = dot2(w3[p+3], h3, a3);
      }
    }
    const float ia = sigm(a0);
    const float fa = sigm(a1);
    const float ga = tanh_f(a2);
    const float oa = sigm(a3);
    c = fmaf(fa, c, ia * ga);
    h = oa * tanh_f(c);
    asm volatile("" ::: "memory");
    hbuf16[k] = (_Float16)h;               // publish for next step (same-wave FIFO)
    asm volatile("" ::: "memory");
  };

  // ---- main phase: T steps in chunks of 64
  float s = fcb;
  for (int tc = 0; tc < T; tc += 64) {
    const float xv = x[(long)row * T + tc + k];   // coalesced chunk load
#pragma unroll 1
    for (int i = 0; i < 64; ++i) {
      cell(rdlane(xv, i));
      st[k][i] = h * fcw;                  // conflict-free (stride 65)
    }
    // transpose-reduce: lane t sums column t -> out[tc + t]
    s = fcb;
#pragma unroll
    for (int j = 0; j < 64; ++j) s += st[j][k];   // conflict-free per j
    asm volatile("" ::: "memory");
    out[(long)row * OT + tc + k] = s;      // coalesced store
  }

  // ---- future phase: feedback out -> x, butterfly reduce each step
  float out_prev = rdlane(s, 63);          // out[T-1]
  float obuf = 0.f;
  for (int t = T; t < OT; ++t) {
    cell(out_prev);
    float p = h * fcw;
#pragma unroll
    for (int off = 32; off > 0; off >>= 1) p += __shfl_xor(p, off, 64);
    const float out_t = p + fcb;
    obuf = (k == (t & 63)) ? out_t : obuf;
    if ((t & 63) == 63)
      out[(long)row * OT + (t - 63) + k] = obuf;  // coalesced
    out_prev = out_t;
  }
}

extern "C" void kernel_launch(void* const* d_in, const int* in_sizes, int n_in,
                              void* d_out, int out_size, void* d_ws, size_t ws_size,
                              hipStream_t stream) {
  const float* x    = (const float*)d_in[0];
  const float* W_ih = (const float*)d_in[1];
  const float* W_hh = (const float*)d_in[2];
  const float* b_ih = (const float*)d_in[3];
  const float* b_hh = (const float*)d_in[4];
  const float* fc_w = (const float*)d_in[5];
  const float* fc_b = (const float*)d_in[6];
  float* out = (float*)d_out;

  const int B  = 2048;
  const int T  = in_sizes[0] / B;   // 2048
  const int OT = out_size / B;      // 2176

  lstm_kernel<<<dim3(B), dim3(64), 0, stream>>>(x, W_ih, W_hh, b_ih, b_hh,
                                                fc_w, fc_b, out, T, OT);
}